// Round 14
// baseline (646.602 us; speedup 1.0000x reference)
//
#include <hip/hip_runtime.h>
#include <hip/hip_bf16.h>

#define LEAKY(v) ((v) > 0.f ? (v) : 0.2f * (v))

typedef __attribute__((ext_vector_type(8))) short s8;          // 8 bf16 (4 VGPRs)
typedef __attribute__((ext_vector_type(4))) float f4;          // 4 fp32 acc
typedef __attribute__((ext_vector_type(4))) unsigned short us4;

__device__ __forceinline__ unsigned short f_to_bf16(float f) {
    union { float f; unsigned int i; } v; v.f = f;
    unsigned int x = v.i;
    return (unsigned short)((x + 0x7fffu + ((x >> 16) & 1u)) >> 16);
}

__device__ __forceinline__ float2 bf2_to_f2(unsigned int u) {
    union { unsigned int i; float f; } a, b;
    a.i = (u & 0xffffu) << 16;
    b.i = u & 0xffff0000u;
    float2 r; r.x = a.f; r.y = b.f;
    return r;
}

struct ConstBuf {
    float ws[3][4];      // dot(W[h,:], a_s[h,:])
    float wd[3][4];      // dot(W[h,:], a_d[h,:])
    float M[3][3][4];    // [branch][attr_k][head]
    float G[12][128];    // folded branch-W through Wf, PERMUTED: G'[k][(j&7)*16+(j>>3)]
    float bias2[128];    // bf + concat-bias through Wf, same permutation
};
#define CB_FLOATS 1724   // 12+12+36+1536+128

struct BranchW { const float *W, *as_, *ad_, *ae, *We, *b; };
struct PreArgs { BranchW br[3]; const float *Wf, *bf; ConstBuf* cb; };

// --- fused precompute: blk0 consts; blk1,2 W2/W3 swizzle; blk3 Wc1 swizzle;
// --- blk4+ deg=0
__global__ void k_pre_all(PreArgs A, const float* __restrict__ W2, unsigned short* __restrict__ wf2,
                          const float* __restrict__ W3, unsigned short* __restrict__ wf3,
                          const float* __restrict__ Wc1, unsigned short* __restrict__ wc1f,
                          int* __restrict__ deg, int N) {
    int t = threadIdx.x; // 256 threads
    if (blockIdx.x == 0) {
        if (t < 24) {
            int b = t / 8, r = t % 8, h = r & 3; bool isd = r >= 4;
            const float* a = isd ? A.br[b].ad_ : A.br[b].as_;
            float s = 0.f;
            for (int c = 0; c < 16; ++c) s += A.br[b].W[h * 16 + c] * a[h * 16 + c];
            if (isd) A.cb->wd[b][h] = s; else A.cb->ws[b][h] = s;
        }
        if (t >= 32 && t < 68) {
            int id = t - 32, b = id / 12, k = (id % 12) / 4, h = id & 3;
            float s = 0.f;
            for (int c = 0; c < 16; ++c) s += A.br[b].We[k * 64 + h * 16 + c] * A.br[b].ae[h * 16 + c];
            A.cb->M[b][k][h] = s;
        }
        if (t >= 128) {
            int j = t - 128;
            float s = A.bf[j];
            for (int b = 0; b < 3; ++b)
                for (int i = 0; i < 64; ++i)
                    s += A.br[b].b[i] * A.Wf[(b * 64 + i) * 128 + j];
            A.cb->bias2[(j & 7) * 16 + (j >> 3)] = s;   // permuted
        }
        for (int id = t; id < 1536; id += 256) {
            int r = id >> 7, j = id & 127, b = r >> 2, h = r & 3;
            float s = 0.f;
            for (int c = 0; c < 16; ++c)
                s += A.br[b].W[h * 16 + c] * A.Wf[(b * 64 + h * 16 + c) * 128 + j];
            A.cb->G[r][(j & 7) * 16 + (j >> 3)] = s;    // permuted
        }
    } else if (blockIdx.x <= 2) {
        const float* W = (blockIdx.x == 1) ? W2 : W3;
        unsigned short* out = (blockIdx.x == 1) ? wf2 : wf3;
        for (int i = t; i < 16384; i += 256) {
            int j = i & 7, lane = (i >> 3) & 63, kk = (i >> 9) & 3, ct = i >> 11;
            int k = kk * 32 + (lane >> 4) * 8 + j;
            int n = ct * 16 + (lane & 15);
            out[i] = f_to_bf16(W[k * 128 + n]);
        }
    } else if (blockIdx.x == 3) {
        for (int i = t; i < 8192; i += 256) {
            int j = i & 7, lane = (i >> 3) & 63, kk = (i >> 9) & 3, ct = i >> 11; // ct 0..3
            int k = kk * 32 + (lane >> 4) * 8 + j;
            int col = ct * 16 + (lane & 15);
            wc1f[i] = f_to_bf16(Wc1[k * 64 + col]);
        }
    } else {
        int idx = (blockIdx.x - 4) * 256 + t;
        if (idx < N) deg[idx] = 0;
    }
}

// ---------------- CSR build ----------------
__global__ void k_count(const int* __restrict__ ei, int E, int* __restrict__ deg) {
    int e = blockIdx.x * blockDim.x + threadIdx.x;
    if (e < E) atomicAdd(&deg[ei[E + e]], 1);
}

#define SCAN_EPB 2048

__global__ void k_scan1(const int* __restrict__ deg, int* __restrict__ off,
                        int* __restrict__ partials, int total) {
    __shared__ int sd[256];
    int t = threadIdx.x;
    int base = blockIdx.x * SCAN_EPB + t * 8;
    int v[8];
    int s = 0;
    #pragma unroll
    for (int i = 0; i < 8; ++i) {
        int idx = base + i;
        v[i] = (idx < total - 1) ? deg[idx] : 0;
        s += v[i];
    }
    sd[t] = s;
    __syncthreads();
    #pragma unroll
    for (int ofs = 1; ofs < 256; ofs <<= 1) {
        int u = (t >= ofs) ? sd[t - ofs] : 0;
        __syncthreads();
        sd[t] += u;
        __syncthreads();
    }
    if (t == 255) partials[blockIdx.x] = sd[255];
    int run = sd[t] - s;
    #pragma unroll
    for (int i = 0; i < 8; ++i) {
        int idx = base + i;
        if (idx < total) off[idx] = run;
        run += v[i];
    }
}

// adds exclusive prefix of block partials (<=25 of them) inline
__global__ void k_scan3(int* __restrict__ off, const int* __restrict__ partials,
                        int* __restrict__ cursor, int total) {
    int idx = blockIdx.x * blockDim.x + threadIdx.x;
    if (idx < total) {
        int pb = idx / SCAN_EPB;
        int addv = 0;
        for (int j = 0; j < pb; ++j) addv += partials[j];
        int v = off[idx] + addv;
        off[idx] = v;
        if (idx < total - 1) cursor[idx] = v;
    }
}

// XCD-partitioned scatter (blockIdx&7 = dst range = XCD), plain loads (R11 best)
// rec = (a0, a1, a2, bits{src | maskbits<<16})   [src < 2^16]
__global__ void k_scatter(const int* __restrict__ ei, const float* __restrict__ attr,
                          const int* __restrict__ mt, const int* __restrict__ mg,
                          const int* __restrict__ mp, int E, int chunk,
                          int* __restrict__ cursor, float4* __restrict__ rec) {
    int r = blockIdx.x & 7;
    int slice = blockIdx.x >> 3;
    int e = slice * 256 + threadIdx.x;
    if (e >= E) return;
    int d = ei[E + e];
    if ((unsigned)(d - r * chunk) >= (unsigned)chunk) return;
    int p = atomicAdd(&cursor[d], 1);
    float4 rr;
    rr.x = attr[e * 3 + 0];
    rr.y = attr[e * 3 + 1];
    rr.z = attr[e * 3 + 2];
    unsigned int bits = (mt[e] != 0 ? 1u : 0u) | (mg[e] != 0 ? 2u : 0u) | (mp[e] != 0 ? 4u : 0u);
    rr.w = __int_as_float((int)((unsigned)ei[e] | (bits << 16)));
    rec[p] = rr;
}

// ------- branch GATs + fusion: 4 lanes per node -> h1 (bf16) ---------
// 4-lane groups: butterfly is 2 rounds (vs 4), S-redundancy x4 (vs x16).
__global__ void k_branch(const float* __restrict__ x, const int* __restrict__ off,
                         const float4* __restrict__ rec, int* __restrict__ csr_src,
                         const ConstBuf* __restrict__ cb, unsigned short* __restrict__ h1, int N) {
    __shared__ float sc[CB_FLOATS]; // ws|wd|M (60), G' (1536), bias2' (128)
    for (int i = threadIdx.x; i < CB_FLOATS; i += 256) sc[i] = ((const float*)cb)[i];
    __syncthreads();
    int g = threadIdx.x >> 2, l = threadIdx.x & 3;
    int n = blockIdx.x * 64 + g;
    if (n >= N) return;

    float num[12], den[12], asum[9], cnt[3];
    #pragma unroll
    for (int i = 0; i < 12; ++i) { num[i] = 0.f; den[i] = 0.f; }
    #pragma unroll
    for (int i = 0; i < 9; ++i) asum[i] = 0.f;
    cnt[0] = cnt[1] = cnt[2] = 0.f;

    float xn = x[n];
    int beg = off[n], end = off[n + 1];
    for (int p = beg + l; p < end; p += 4) {
        float4 r = rec[p];
        unsigned int packed = (unsigned int)__float_as_int(r.w);
        int src = (int)(packed & 0xffffu);
        unsigned int bits = packed >> 16;
        csr_src[p] = src;
        float xs = x[src];
        float a0 = r.x, a1 = r.y, a2 = r.z;
        #pragma unroll
        for (int b = 0; b < 3; ++b) {
            if ((bits >> b) & 1u) {
                cnt[b] += 1.f;
                asum[b * 3 + 0] += a0; asum[b * 3 + 1] += a1; asum[b * 3 + 2] += a2;
                #pragma unroll
                for (int h = 0; h < 4; ++h) {
                    float al = xs * sc[b * 4 + h] + xn * sc[12 + b * 4 + h]
                             + a0 * sc[24 + b * 12 + 0 + h]
                             + a1 * sc[24 + b * 12 + 4 + h]
                             + a2 * sc[24 + b * 12 + 8 + h];
                    al = LEAKY(al);
                    float ex = __expf(al);
                    den[b * 4 + h] += ex;
                    num[b * 4 + h] += ex * xs;
                }
            }
        }
    }
    // butterfly over 4-lane group: 2 rounds
    #pragma unroll
    for (int m = 1; m < 4; m <<= 1) {
        #pragma unroll
        for (int i = 0; i < 12; ++i) {
            num[i] += __shfl_xor(num[i], m, 64);
            den[i] += __shfl_xor(den[i], m, 64);
        }
        #pragma unroll
        for (int i = 0; i < 9; ++i) asum[i] += __shfl_xor(asum[i], m, 64);
        #pragma unroll
        for (int i = 0; i < 3; ++i) cnt[i] += __shfl_xor(cnt[i], m, 64);
    }
    float S[12];
    #pragma unroll
    for (int b = 0; b < 3; ++b) {
        float inv = 1.f / fmaxf(cnt[b], 1.f);
        float l0 = asum[b * 3 + 0] * inv, l1 = asum[b * 3 + 1] * inv, l2 = asum[b * 3 + 2] * inv;
        #pragma unroll
        for (int h = 0; h < 4; ++h) {
            float lp = xn * (sc[b * 4 + h] + sc[12 + b * 4 + h])
                     + l0 * sc[24 + b * 12 + 0 + h]
                     + l1 * sc[24 + b * 12 + 4 + h]
                     + l2 * sc[24 + b * 12 + 8 + h];
            lp = LEAKY(lp);
            float exl = __expf(lp);
            float sden = den[b * 4 + h] + exl;
            S[b * 4 + h] = (num[b * 4 + h] + exl * xn) / sden;
        }
    }
    // fused h1 = relu(S @ G + bias2); lane l -> cols l*32..l*32+31.
    // permuted addr for col j=l*32+q8*8+q2*2+s: (q2*2+s)*16 + l*4 + q8
    // -> 4 distinct addrs per wave-read, banks 4 apart: conflict-free
    #pragma unroll
    for (int q8 = 0; q8 < 4; ++q8) {
        unsigned int o[4];
        #pragma unroll
        for (int q2 = 0; q2 < 4; ++q2) {
            float v0, v1;
            #pragma unroll
            for (int s = 0; s < 2; ++s) {
                int addr = (q2 * 2 + s) * 16 + l * 4 + q8;
                float a = sc[60 + 1536 + addr];
                #pragma unroll
                for (int k = 0; k < 12; ++k) a += S[k] * sc[60 + k * 128 + addr];
                if (s == 0) v0 = fmaxf(a, 0.f); else v1 = fmaxf(a, 0.f);
            }
            o[q2] = (unsigned int)f_to_bf16(v0) | ((unsigned int)f_to_bf16(v1) << 16);
        }
        uint4 pack; pack.x = o[0]; pack.y = o[1]; pack.z = o[2]; pack.w = o[3];
        *(uint4*)(h1 + (size_t)n * 128 + l * 32 + q8 * 8) = pack;
    }
}

// ---- MFMA [N,128]@[128,128] (bf16 in) -> bf16 hx + FUSED attention scores ----
__global__ void k_mm128b(const unsigned short* __restrict__ A, const unsigned short* __restrict__ wf,
                         const float* __restrict__ a_s, const float* __restrict__ a_d,
                         unsigned short* __restrict__ hxb, float* __restrict__ as_,
                         float* __restrict__ ad_, int N) {
    __shared__ unsigned short sA[64 * 136]; // 272B padded rows
    __shared__ unsigned short sW[16384];    // 32 KB fragment-layout W
    int tid = threadIdx.x;
    int base = blockIdx.x * 64;
    const float4* wf4 = (const float4*)wf;
    float4* sW4 = (float4*)sW;
    #pragma unroll
    for (int i = 0; i < 8; ++i) sW4[tid + i * 256] = wf4[tid + i * 256];
    #pragma unroll
    for (int i = 0; i < 4; ++i) {
        int f = tid + i * 256;            // uint4 index into 64x128 bf16 tile
        int row = f >> 4, c8 = f & 15;
        int n = base + row;
        uint4 v = (n < N) ? ((const uint4*)A)[(size_t)n * 16 + c8]
                          : make_uint4(0u, 0u, 0u, 0u);
        *(uint4*)(&sA[row * 136 + c8 * 8]) = v;
    }
    __syncthreads();
    int wv = tid >> 6, lane = tid & 63;
    int q = lane >> 4, l15 = lane & 15;
    int rowbase = wv * 16;
    s8 af[4];
    #pragma unroll
    for (int kk = 0; kk < 4; ++kk)
        af[kk] = *(const s8*)(&sA[(rowbase + l15) * 136 + kk * 32 + q * 8]);
    float as8[8], ad8[8];
    #pragma unroll
    for (int ct = 0; ct < 8; ++ct) { as8[ct] = a_s[ct * 16 + l15]; ad8[ct] = a_d[ct * 16 + l15]; }
    float ss[4][4], sdd[4][4];
    #pragma unroll
    for (int r = 0; r < 4; ++r)
        #pragma unroll
        for (int hh = 0; hh < 4; ++hh) { ss[r][hh] = 0.f; sdd[r][hh] = 0.f; }
    #pragma unroll
    for (int ct = 0; ct < 8; ++ct) {
        f4 acc = {0.f, 0.f, 0.f, 0.f};
        #pragma unroll
        for (int kk = 0; kk < 4; ++kk) {
            s8 bfr = *(const s8*)(&sW[((ct * 4 + kk) * 64 + lane) * 8]);
            acc = __builtin_amdgcn_mfma_f32_16x16x32_bf16(af[kk], bfr, acc, 0, 0, 0);
        }
        int hh = ct >> 1;
        float asv = as8[ct], adv = ad8[ct];
        #pragma unroll
        for (int r = 0; r < 4; ++r) {
            int n = base + rowbase + q * 4 + r;
            if (n < N) hxb[(size_t)n * 128 + ct * 16 + l15] = f_to_bf16(acc[r]);
            ss[r][hh] += acc[r] * asv;
            sdd[r][hh] += acc[r] * adv;
        }
    }
    #pragma unroll
    for (int m = 1; m < 16; m <<= 1) {
        #pragma unroll
        for (int r = 0; r < 4; ++r)
            #pragma unroll
            for (int hh = 0; hh < 4; ++hh) {
                ss[r][hh] += __shfl_xor(ss[r][hh], m, 64);
                sdd[r][hh] += __shfl_xor(sdd[r][hh], m, 64);
            }
    }
    #pragma unroll
    for (int hh = 0; hh < 4; ++hh) {
        if (l15 == hh) {
            #pragma unroll
            for (int r = 0; r < 4; ++r) {
                int n = base + rowbase + q * 4 + r;
                if (n < N) {
                    as_[(size_t)n * 4 + hh] = ss[r][hh];
                    ad_[(size_t)n * 4 + hh] = sdd[r][hh];
                }
            }
        }
    }
}

// ------- GAT aggregation: wave per node; cooperative exp; bf16 out ------------
__global__ void k_gatagg(const unsigned short* __restrict__ hxb, const float* __restrict__ as_,
                         const float* __restrict__ ad_, const float* __restrict__ b,
                         const int* __restrict__ off, const int* __restrict__ csr_src,
                         unsigned short* __restrict__ out, int N) {
    int wave = threadIdx.x >> 6, lane = threadIdx.x & 63;
    int n = blockIdx.x * 4 + wave;
    if (n >= N) return;
    int h = lane >> 4;
    int lofs = lane * 2;
    int hm = lane & 3;
    int im = lane >> 2;
    float adn = ad_[(size_t)n * 4 + h];
    float adnm = ad_[(size_t)n * 4 + hm];
    int beg = off[n], end = off[n + 1];
    float acc0 = 0.f, acc1 = 0.f, accd = 0.f;
    for (int p = beg; p < end; p += 16) {
        int pm = p + im;
        bool vm = pm < end;
        int sm = csr_src[vm ? pm : beg];
        float em = as_[(size_t)sm * 4 + hm];
        float exm = vm ? __expf(LEAKY(em + adnm)) : 0.f;
        #pragma unroll
        for (int i = 0; i < 16; ++i) {
            int sb = __shfl(sm, i * 4, 64);
            float ex = __shfl(exm, i * 4 + h, 64);
            unsigned int u = *(const unsigned int*)(hxb + (size_t)sb * 128 + lofs);
            float2 v = bf2_to_f2(u);
            acc0 += ex * v.x; acc1 += ex * v.y; accd += ex;
        }
    }
    float aln = LEAKY(as_[(size_t)n * 4 + h] + adn);
    float exl = __expf(aln);
    unsigned int un = *(const unsigned int*)(hxb + (size_t)n * 128 + lofs);
    float2 vn = bf2_to_f2(un);
    float inv = 1.f / (accd + exl);
    float o0 = fmaxf((acc0 + exl * vn.x) * inv + b[lofs + 0], 0.f);
    float o1 = fmaxf((acc1 + exl * vn.y) * inv + b[lofs + 1], 0.f);
    unsigned int pk = (unsigned int)f_to_bf16(o0) | ((unsigned int)f_to_bf16(o1) << 16);
    *(unsigned int*)(out + (size_t)n * 128 + lofs) = pk;
}

// ------- classifier via MFMA + log_softmax: 64 nodes/block ----------
__global__ void k_cls(const unsigned short* __restrict__ h3, const unsigned short* __restrict__ wc1f,
                      const float* __restrict__ bc1, const float* __restrict__ Wc2,
                      const float* __restrict__ bc2, float* __restrict__ out, int N) {
    __shared__ unsigned short sA[64 * 136];
    __shared__ unsigned short sW[8192];   // 16 KB Wc1 frags
    int tid = threadIdx.x;
    int base = blockIdx.x * 64;
    const float4* wf4 = (const float4*)wc1f;
    float4* sW4 = (float4*)sW;
    #pragma unroll
    for (int i = 0; i < 4; ++i) sW4[tid + i * 256] = wf4[tid + i * 256];
    #pragma unroll
    for (int i = 0; i < 4; ++i) {
        int f = tid + i * 256;
        int row = f >> 4, c8 = f & 15;
        int n = base + row;
        uint4 v = (n < N) ? ((const uint4*)h3)[(size_t)n * 16 + c8]
                          : make_uint4(0u, 0u, 0u, 0u);
        *(uint4*)(&sA[row * 136 + c8 * 8]) = v;
    }
    __syncthreads();
    int wv = tid >> 6, lane = tid & 63;
    int q = lane >> 4, l15 = lane & 15;
    int rowbase = wv * 16;
    s8 af[4];
    #pragma unroll
    for (int kk = 0; kk < 4; ++kk)
        af[kk] = *(const s8*)(&sA[(rowbase + l15) * 136 + kk * 32 + q * 8]);
    float p[4][5];
    #pragma unroll
    for (int r = 0; r < 4; ++r)
        #pragma unroll
        for (int c = 0; c < 5; ++c) p[r][c] = 0.f;
    #pragma unroll
    for (int ct = 0; ct < 4; ++ct) {
        f4 acc = {0.f, 0.f, 0.f, 0.f};
        #pragma unroll
        for (int kk = 0; kk < 4; ++kk) {
            s8 bfr = *(const s8*)(&sW[((ct * 4 + kk) * 64 + lane) * 8]);
            acc = __builtin_amdgcn_mfma_f32_16x16x32_bf16(af[kk], bfr, acc, 0, 0, 0);
        }
        int col = ct * 16 + l15;
        float bcv = bc1[col];
        float w2v[5];
        #pragma unroll
        for (int c = 0; c < 5; ++c) w2v[c] = Wc2[col * 5 + c];
        #pragma unroll
        for (int r = 0; r < 4; ++r) {
            float t = fmaxf(acc[r] + bcv, 0.f);
            #pragma unroll
            for (int c = 0; c < 5; ++c) p[r][c] += t * w2v[c];
        }
    }
    #pragma unroll
    for (int m = 1; m < 16; m <<= 1) {
        #pragma unroll
        for (int r = 0; r < 4; ++r)
            #pragma unroll
            for (int c = 0; c < 5; ++c)
                p[r][c] += __shfl_xor(p[r][c], m, 64);
    }
    if (l15 == 0) {
        #pragma unroll
        for (int r = 0; r < 4; ++r) {
            int n = base + rowbase + q * 4 + r;
            if (n >= N) continue;
            float l[5], mx = -1e30f;
            #pragma unroll
            for (int c = 0; c < 5; ++c) { l[c] = p[r][c] + bc2[c]; mx = fmaxf(mx, l[c]); }
            float s = 0.f;
            #pragma unroll
            for (int c = 0; c < 5; ++c) s += __expf(l[c] - mx);
            float lse = mx + __logf(s);
            #pragma unroll
            for (int c = 0; c < 5; ++c) out[(size_t)n * 5 + c] = l[c] - lse;
        }
    }
}

extern "C" void kernel_launch(void* const* d_in, const int* in_sizes, int n_in,
                              void* d_out, int out_size, void* d_ws, size_t ws_size,
                              hipStream_t stream) {
    const float* x    = (const float*)d_in[0];
    const int*   ei   = (const int*)d_in[1];
    const float* attr = (const float*)d_in[2];
    const int*   mt   = (const int*)d_in[3];
    const int*   mg   = (const int*)d_in[4];
    const int*   mp   = (const int*)d_in[5];
    const float* Wf   = (const float*)d_in[24];
    const float* bf   = (const float*)d_in[25];
    const float* W2   = (const float*)d_in[26];
    const float* a2s  = (const float*)d_in[27];
    const float* a2d  = (const float*)d_in[28];
    const float* b2   = (const float*)d_in[29];
    const float* W3   = (const float*)d_in[30];
    const float* a3s  = (const float*)d_in[31];
    const float* a3d  = (const float*)d_in[32];
    const float* b3   = (const float*)d_in[33];
    const float* Wc1  = (const float*)d_in[34];
    const float* bc1  = (const float*)d_in[35];
    const float* Wc2  = (const float*)d_in[36];
    const float* bc2  = (const float*)d_in[37];

    int N = in_sizes[0];
    int E = in_sizes[1] / 2;

    char* w = (char*)d_ws;
    auto alloc = [&](size_t bytes) {
        char* p = w;
        w += (bytes + 255) & ~(size_t)255;
        return p;
    };
    int* off      = (int*)alloc((size_t)(N + 1) * 4);
    int* cursor   = (int*)alloc((size_t)N * 4);
    int* deg      = (int*)alloc((size_t)N * 4);
    int* partials = (int*)alloc(1024 * 4);
    int* csr_src  = (int*)alloc((size_t)E * 4);
    ConstBuf* cb  = (ConstBuf*)alloc(sizeof(ConstBuf));
    float* as_    = (float*)alloc((size_t)N * 4 * 4);
    float* ad_    = (float*)alloc((size_t)N * 4 * 4);
    unsigned short* xb = (unsigned short*)alloc((size_t)N * 256);  // h1/h2/h3 bf16
    float4* rec   = (float4*)alloc((size_t)E * 16);
    unsigned short* hxb = (unsigned short*)alloc((size_t)N * 256);
    unsigned short* wf2 = (unsigned short*)alloc(16384 * 2);
    unsigned short* wf3 = (unsigned short*)alloc(16384 * 2);
    unsigned short* wc1f = (unsigned short*)alloc(8192 * 2);

    PreArgs pa;
    for (int b = 0; b < 3; ++b) {
        pa.br[b].W   = (const float*)d_in[6 + b * 6 + 0];
        pa.br[b].as_ = (const float*)d_in[6 + b * 6 + 1];
        pa.br[b].ad_ = (const float*)d_in[6 + b * 6 + 2];
        pa.br[b].ae  = (const float*)d_in[6 + b * 6 + 3];
        pa.br[b].We  = (const float*)d_in[6 + b * 6 + 4];
        pa.br[b].b   = (const float*)d_in[6 + b * 6 + 5];
    }
    pa.Wf = Wf; pa.bf = bf; pa.cb = cb;

    int total = N + 1;
    int nScanBlocks = (total + SCAN_EPB - 1) / SCAN_EPB;

    hipLaunchKernelGGL(k_pre_all, dim3(4 + (N + 255) / 256), dim3(256), 0, stream,
                       pa, W2, wf2, W3, wf3, Wc1, wc1f, deg, N);
    int gE = (E + 255) / 256;
    hipLaunchKernelGGL(k_count, dim3(gE), dim3(256), 0, stream, ei, E, deg);
    hipLaunchKernelGGL(k_scan1, dim3(nScanBlocks), dim3(256), 0, stream, deg, off, partials, total);
    hipLaunchKernelGGL(k_scan3, dim3((total + 255) / 256), dim3(256), 0, stream,
                       off, partials, cursor, total);
    int chunk = (N + 7) / 8;
    hipLaunchKernelGGL(k_scatter, dim3(gE * 8), dim3(256), 0, stream,
                       ei, attr, mt, mg, mp, E, chunk, cursor, rec);
    hipLaunchKernelGGL(k_branch, dim3((N + 63) / 64), dim3(256), 0, stream,
                       x, off, rec, csr_src, cb, xb, N);
    // conv2
    hipLaunchKernelGGL(k_mm128b, dim3((N + 63) / 64), dim3(256), 0, stream,
                       xb, wf2, a2s, a2d, hxb, as_, ad_, N);
    hipLaunchKernelGGL(k_gatagg, dim3((N + 3) / 4), dim3(256), 0, stream,
                       hxb, as_, ad_, b2, off, csr_src, xb, N);
    // conv3
    hipLaunchKernelGGL(k_mm128b, dim3((N + 63) / 64), dim3(256), 0, stream,
                       xb, wf3, a3s, a3d, hxb, as_, ad_, N);
    hipLaunchKernelGGL(k_gatagg, dim3((N + 3) / 4), dim3(256), 0, stream,
                       hxb, as_, ad_, b3, off, csr_src, xb, N);
    // classifier (MFMA)
    hipLaunchKernelGGL(k_cls, dim3((N + 63) / 64), dim3(256), 0, stream,
                       xb, wc1f, bc1, Wc2, bc2, (float*)d_out, N);
}

// Round 15
// 402.236 us; speedup vs baseline: 1.6075x; 1.6075x over previous
//
#include <hip/hip_runtime.h>
#include <hip/hip_bf16.h>

#define LEAKY(v) ((v) > 0.f ? (v) : 0.2f * (v))

typedef __attribute__((ext_vector_type(8))) short s8;          // 8 bf16 (4 VGPRs)
typedef __attribute__((ext_vector_type(4))) float f4;          // 4 fp32 acc
typedef __attribute__((ext_vector_type(4))) unsigned short us4;

__device__ __forceinline__ unsigned short f_to_bf16(float f) {
    union { float f; unsigned int i; } v; v.f = f;
    unsigned int x = v.i;
    return (unsigned short)((x + 0x7fffu + ((x >> 16) & 1u)) >> 16);
}

__device__ __forceinline__ float2 bf2_to_f2(unsigned int u) {
    union { unsigned int i; float f; } a, b;
    a.i = (u & 0xffffu) << 16;
    b.i = u & 0xffff0000u;
    float2 r; r.x = a.f; r.y = b.f;
    return r;
}

struct ConstBuf {
    float ws[3][4];      // dot(W[h,:], a_s[h,:])
    float wd[3][4];      // dot(W[h,:], a_d[h,:])
    float M[3][3][4];    // [branch][attr_k][head]
    float G[12][128];    // folded branch-W through Wf
    float bias2[128];    // bf + concat-bias through Wf
};
#define CB_FLOATS 1724   // 12+12+36+1536+128

struct BranchW { const float *W, *as_, *ad_, *ae, *We, *b; };
struct PreArgs { BranchW br[3]; const float *Wf, *bf; ConstBuf* cb; };

// --- fused precompute: blk0 consts; blk1,2 W2/W3 swizzle; blk3 Wc1 swizzle;
// --- blk4+ deg=0
__global__ void k_pre_all(PreArgs A, const float* __restrict__ W2, unsigned short* __restrict__ wf2,
                          const float* __restrict__ W3, unsigned short* __restrict__ wf3,
                          const float* __restrict__ Wc1, unsigned short* __restrict__ wc1f,
                          int* __restrict__ deg, int N) {
    int t = threadIdx.x; // 256 threads
    if (blockIdx.x == 0) {
        if (t < 24) {
            int b = t / 8, r = t % 8, h = r & 3; bool isd = r >= 4;
            const float* a = isd ? A.br[b].ad_ : A.br[b].as_;
            float s = 0.f;
            for (int c = 0; c < 16; ++c) s += A.br[b].W[h * 16 + c] * a[h * 16 + c];
            if (isd) A.cb->wd[b][h] = s; else A.cb->ws[b][h] = s;
        }
        if (t >= 32 && t < 68) {
            int id = t - 32, b = id / 12, k = (id % 12) / 4, h = id & 3;
            float s = 0.f;
            for (int c = 0; c < 16; ++c) s += A.br[b].We[k * 64 + h * 16 + c] * A.br[b].ae[h * 16 + c];
            A.cb->M[b][k][h] = s;
        }
        if (t >= 128) {
            int j = t - 128;
            float s = A.bf[j];
            for (int b = 0; b < 3; ++b)
                for (int i = 0; i < 64; ++i)
                    s += A.br[b].b[i] * A.Wf[(b * 64 + i) * 128 + j];
            A.cb->bias2[j] = s;
        }
        for (int id = t; id < 1536; id += 256) {
            int r = id >> 7, j = id & 127, b = r >> 2, h = r & 3;
            float s = 0.f;
            for (int c = 0; c < 16; ++c)
                s += A.br[b].W[h * 16 + c] * A.Wf[(b * 64 + h * 16 + c) * 128 + j];
            A.cb->G[r][j] = s;
        }
    } else if (blockIdx.x <= 2) {
        const float* W = (blockIdx.x == 1) ? W2 : W3;
        unsigned short* out = (blockIdx.x == 1) ? wf2 : wf3;
        for (int i = t; i < 16384; i += 256) {
            int j = i & 7, lane = (i >> 3) & 63, kk = (i >> 9) & 3, ct = i >> 11;
            int k = kk * 32 + (lane >> 4) * 8 + j;
            int n = ct * 16 + (lane & 15);
            out[i] = f_to_bf16(W[k * 128 + n]);
        }
    } else if (blockIdx.x == 3) {
        for (int i = t; i < 8192; i += 256) {
            int j = i & 7, lane = (i >> 3) & 63, kk = (i >> 9) & 3, ct = i >> 11; // ct 0..3
            int k = kk * 32 + (lane >> 4) * 8 + j;
            int col = ct * 16 + (lane & 15);
            wc1f[i] = f_to_bf16(Wc1[k * 64 + col]);
        }
    } else {
        int idx = (blockIdx.x - 4) * 256 + t;
        if (idx < N) deg[idx] = 0;
    }
}

// ---------------- CSR build ----------------
__global__ void k_count(const int* __restrict__ ei, int E, int* __restrict__ deg) {
    int e = blockIdx.x * blockDim.x + threadIdx.x;
    if (e < E) atomicAdd(&deg[ei[E + e]], 1);
}

#define SCAN_EPB 2048

__global__ void k_scan1(const int* __restrict__ deg, int* __restrict__ off,
                        int* __restrict__ partials, int total) {
    __shared__ int sd[256];
    int t = threadIdx.x;
    int base = blockIdx.x * SCAN_EPB + t * 8;
    int v[8];
    int s = 0;
    #pragma unroll
    for (int i = 0; i < 8; ++i) {
        int idx = base + i;
        v[i] = (idx < total - 1) ? deg[idx] : 0;
        s += v[i];
    }
    sd[t] = s;
    __syncthreads();
    #pragma unroll
    for (int ofs = 1; ofs < 256; ofs <<= 1) {
        int u = (t >= ofs) ? sd[t - ofs] : 0;
        __syncthreads();
        sd[t] += u;
        __syncthreads();
    }
    if (t == 255) partials[blockIdx.x] = sd[255];
    int run = sd[t] - s;
    #pragma unroll
    for (int i = 0; i < 8; ++i) {
        int idx = base + i;
        if (idx < total) off[idx] = run;
        run += v[i];
    }
}

// adds exclusive prefix of block partials (<=25 of them) inline
__global__ void k_scan3(int* __restrict__ off, const int* __restrict__ partials,
                        int* __restrict__ cursor, int total) {
    int idx = blockIdx.x * blockDim.x + threadIdx.x;
    if (idx < total) {
        int pb = idx / SCAN_EPB;
        int addv = 0;
        for (int j = 0; j < pb; ++j) addv += partials[j];
        int v = off[idx] + addv;
        off[idx] = v;
        if (idx < total - 1) cursor[idx] = v;
    }
}

// XCD-partitioned scatter: block handles dst-range (blockIdx & 7) over a
// 256-edge slice; writes to a rec line all come from one XCD.
// rec = (a0, a1, a2, bits{src | maskbits<<16})   [src < 2^16]
__global__ void k_scatter(const int* __restrict__ ei, const float* __restrict__ attr,
                          const int* __restrict__ mt, const int* __restrict__ mg,
                          const int* __restrict__ mp, int E, int chunk,
                          int* __restrict__ cursor, float4* __restrict__ rec) {
    int r = blockIdx.x & 7;
    int slice = blockIdx.x >> 3;
    int e = slice * 256 + threadIdx.x;
    if (e >= E) return;
    int d = ei[E + e];
    if ((unsigned)(d - r * chunk) >= (unsigned)chunk) return;
    int p = atomicAdd(&cursor[d], 1);
    float4 rr;
    rr.x = attr[e * 3 + 0];
    rr.y = attr[e * 3 + 1];
    rr.z = attr[e * 3 + 2];
    unsigned int bits = (mt[e] != 0 ? 1u : 0u) | (mg[e] != 0 ? 2u : 0u) | (mp[e] != 0 ? 4u : 0u);
    rr.w = __int_as_float((int)((unsigned)ei[e] | (bits << 16)));
    rec[p] = rr;
}

// ------- branch GATs + fusion: 16 lanes per node -> h1 (bf16) ---------
__global__ void k_branch(const float* __restrict__ x, const int* __restrict__ off,
                         const float4* __restrict__ rec, int* __restrict__ csr_src,
                         const ConstBuf* __restrict__ cb, unsigned short* __restrict__ h1, int N) {
    __shared__ float sc[CB_FLOATS]; // ws|wd|M (60), G (1536), bias2 (128)
    for (int i = threadIdx.x; i < CB_FLOATS; i += 256) sc[i] = ((const float*)cb)[i];
    __syncthreads();
    int g = threadIdx.x >> 4, l = threadIdx.x & 15;
    int n = blockIdx.x * 16 + g;
    if (n >= N) return;

    float num[12], den[12], asum[9], cnt[3];
    #pragma unroll
    for (int i = 0; i < 12; ++i) { num[i] = 0.f; den[i] = 0.f; }
    #pragma unroll
    for (int i = 0; i < 9; ++i) asum[i] = 0.f;
    cnt[0] = cnt[1] = cnt[2] = 0.f;

    float xn = x[n];
    int beg = off[n], end = off[n + 1];
    for (int p = beg + l; p < end; p += 16) {
        float4 r = rec[p];
        unsigned int packed = (unsigned int)__float_as_int(r.w);
        int src = (int)(packed & 0xffffu);
        unsigned int bits = packed >> 16;
        csr_src[p] = src;
        float xs = x[src];
        float a0 = r.x, a1 = r.y, a2 = r.z;
        #pragma unroll
        for (int b = 0; b < 3; ++b) {
            if ((bits >> b) & 1u) {
                cnt[b] += 1.f;
                asum[b * 3 + 0] += a0; asum[b * 3 + 1] += a1; asum[b * 3 + 2] += a2;
                #pragma unroll
                for (int h = 0; h < 4; ++h) {
                    float al = xs * sc[b * 4 + h] + xn * sc[12 + b * 4 + h]
                             + a0 * sc[24 + b * 12 + 0 + h]
                             + a1 * sc[24 + b * 12 + 4 + h]
                             + a2 * sc[24 + b * 12 + 8 + h];
                    al = LEAKY(al);
                    float ex = __expf(al);
                    den[b * 4 + h] += ex;
                    num[b * 4 + h] += ex * xs;
                }
            }
        }
    }
    #pragma unroll
    for (int m = 1; m < 16; m <<= 1) {
        #pragma unroll
        for (int i = 0; i < 12; ++i) {
            num[i] += __shfl_xor(num[i], m, 64);
            den[i] += __shfl_xor(den[i], m, 64);
        }
        #pragma unroll
        for (int i = 0; i < 9; ++i) asum[i] += __shfl_xor(asum[i], m, 64);
        #pragma unroll
        for (int i = 0; i < 3; ++i) cnt[i] += __shfl_xor(cnt[i], m, 64);
    }
    float S[12];
    #pragma unroll
    for (int b = 0; b < 3; ++b) {
        float inv = 1.f / fmaxf(cnt[b], 1.f);
        float l0 = asum[b * 3 + 0] * inv, l1 = asum[b * 3 + 1] * inv, l2 = asum[b * 3 + 2] * inv;
        #pragma unroll
        for (int h = 0; h < 4; ++h) {
            float lp = xn * (sc[b * 4 + h] + sc[12 + b * 4 + h])
                     + l0 * sc[24 + b * 12 + 0 + h]
                     + l1 * sc[24 + b * 12 + 4 + h]
                     + l2 * sc[24 + b * 12 + 8 + h];
            lp = LEAKY(lp);
            float exl = __expf(lp);
            float sden = den[b * 4 + h] + exl;
            S[b * 4 + h] = (num[b * 4 + h] + exl * xn) / sden;
        }
    }
    int jb = l * 8;
    unsigned int o[4];
    #pragma unroll
    for (int q2 = 0; q2 < 4; ++q2) {
        float v0, v1;
        #pragma unroll
        for (int s = 0; s < 2; ++s) {
            int j = jb + q2 * 2 + s;
            float a = sc[60 + 1536 + j];
            #pragma unroll
            for (int k = 0; k < 12; ++k) a += S[k] * sc[60 + k * 128 + j];
            if (s == 0) v0 = fmaxf(a, 0.f); else v1 = fmaxf(a, 0.f);
        }
        o[q2] = (unsigned int)f_to_bf16(v0) | ((unsigned int)f_to_bf16(v1) << 16);
    }
    uint4 pack; pack.x = o[0]; pack.y = o[1]; pack.z = o[2]; pack.w = o[3];
    *(uint4*)(h1 + (size_t)n * 128 + jb) = pack;
}

// ---- MFMA [N,128]@[128,128] (bf16 in) -> bf16 hx + FUSED attention scores ----
__global__ void k_mm128b(const unsigned short* __restrict__ A, const unsigned short* __restrict__ wf,
                         const float* __restrict__ a_s, const float* __restrict__ a_d,
                         unsigned short* __restrict__ hxb, float* __restrict__ as_,
                         float* __restrict__ ad_, int N) {
    __shared__ unsigned short sA[64 * 136]; // 272B padded rows
    __shared__ unsigned short sW[16384];    // 32 KB fragment-layout W
    int tid = threadIdx.x;
    int base = blockIdx.x * 64;
    const float4* wf4 = (const float4*)wf;
    float4* sW4 = (float4*)sW;
    #pragma unroll
    for (int i = 0; i < 8; ++i) sW4[tid + i * 256] = wf4[tid + i * 256];
    // stage A rows (bf16 direct, uint4 = 8 bf16)
    #pragma unroll
    for (int i = 0; i < 4; ++i) {
        int f = tid + i * 256;            // uint4 index into 64x128 bf16 tile
        int row = f >> 4, c8 = f & 15;
        int n = base + row;
        uint4 v = (n < N) ? ((const uint4*)A)[(size_t)n * 16 + c8]
                          : make_uint4(0u, 0u, 0u, 0u);
        *(uint4*)(&sA[row * 136 + c8 * 8]) = v;
    }
    __syncthreads();
    int wv = tid >> 6, lane = tid & 63;
    int q = lane >> 4, l15 = lane & 15;
    int rowbase = wv * 16;
    s8 af[4];
    #pragma unroll
    for (int kk = 0; kk < 4; ++kk)
        af[kk] = *(const s8*)(&sA[(rowbase + l15) * 136 + kk * 32 + q * 8]);
    float as8[8], ad8[8];
    #pragma unroll
    for (int ct = 0; ct < 8; ++ct) { as8[ct] = a_s[ct * 16 + l15]; ad8[ct] = a_d[ct * 16 + l15]; }
    float ss[4][4], sdd[4][4];
    #pragma unroll
    for (int r = 0; r < 4; ++r)
        #pragma unroll
        for (int hh = 0; hh < 4; ++hh) { ss[r][hh] = 0.f; sdd[r][hh] = 0.f; }
    #pragma unroll
    for (int ct = 0; ct < 8; ++ct) {
        f4 acc = {0.f, 0.f, 0.f, 0.f};
        #pragma unroll
        for (int kk = 0; kk < 4; ++kk) {
            s8 bfr = *(const s8*)(&sW[((ct * 4 + kk) * 64 + lane) * 8]);
            acc = __builtin_amdgcn_mfma_f32_16x16x32_bf16(af[kk], bfr, acc, 0, 0, 0);
        }
        int hh = ct >> 1;
        float asv = as8[ct], adv = ad8[ct];
        #pragma unroll
        for (int r = 0; r < 4; ++r) {
            int n = base + rowbase + q * 4 + r;
            if (n < N) hxb[(size_t)n * 128 + ct * 16 + l15] = f_to_bf16(acc[r]);
            ss[r][hh] += acc[r] * asv;
            sdd[r][hh] += acc[r] * adv;
        }
    }
    #pragma unroll
    for (int m = 1; m < 16; m <<= 1) {
        #pragma unroll
        for (int r = 0; r < 4; ++r)
            #pragma unroll
            for (int hh = 0; hh < 4; ++hh) {
                ss[r][hh] += __shfl_xor(ss[r][hh], m, 64);
                sdd[r][hh] += __shfl_xor(sdd[r][hh], m, 64);
            }
    }
    #pragma unroll
    for (int hh = 0; hh < 4; ++hh) {
        if (l15 == hh) {
            #pragma unroll
            for (int r = 0; r < 4; ++r) {
                int n = base + rowbase + q * 4 + r;
                if (n < N) {
                    as_[(size_t)n * 4 + hh] = ss[r][hh];
                    ad_[(size_t)n * 4 + hh] = sdd[r][hh];
                }
            }
        }
    }
}

// ------- GAT aggregation: wave per node; cooperative exp; bf16 out ------------
__global__ void k_gatagg(const unsigned short* __restrict__ hxb, const float* __restrict__ as_,
                         const float* __restrict__ ad_, const float* __restrict__ b,
                         const int* __restrict__ off, const int* __restrict__ csr_src,
                         unsigned short* __restrict__ out, int N) {
    int wave = threadIdx.x >> 6, lane = threadIdx.x & 63;
    int n = blockIdx.x * 4 + wave;
    if (n >= N) return;
    int h = lane >> 4;
    int lofs = lane * 2;
    int hm = lane & 3;
    int im = lane >> 2;
    float adn = ad_[(size_t)n * 4 + h];
    float adnm = ad_[(size_t)n * 4 + hm];
    int beg = off[n], end = off[n + 1];
    float acc0 = 0.f, acc1 = 0.f, accd = 0.f;
    for (int p = beg; p < end; p += 16) {
        int pm = p + im;
        bool vm = pm < end;
        int sm = csr_src[vm ? pm : beg];
        float em = as_[(size_t)sm * 4 + hm];
        float exm = vm ? __expf(LEAKY(em + adnm)) : 0.f;
        #pragma unroll
        for (int i = 0; i < 16; ++i) {
            int sb = __shfl(sm, i * 4, 64);
            float ex = __shfl(exm, i * 4 + h, 64);
            unsigned int u = *(const unsigned int*)(hxb + (size_t)sb * 128 + lofs);
            float2 v = bf2_to_f2(u);
            acc0 += ex * v.x; acc1 += ex * v.y; accd += ex;
        }
    }
    float aln = LEAKY(as_[(size_t)n * 4 + h] + adn);
    float exl = __expf(aln);
    unsigned int un = *(const unsigned int*)(hxb + (size_t)n * 128 + lofs);
    float2 vn = bf2_to_f2(un);
    float inv = 1.f / (accd + exl);
    float o0 = fmaxf((acc0 + exl * vn.x) * inv + b[lofs + 0], 0.f);
    float o1 = fmaxf((acc1 + exl * vn.y) * inv + b[lofs + 1], 0.f);
    unsigned int pk = (unsigned int)f_to_bf16(o0) | ((unsigned int)f_to_bf16(o1) << 16);
    *(unsigned int*)(out + (size_t)n * 128 + lofs) = pk;
}

// ------- classifier via MFMA + log_softmax: 64 nodes/block ----------
__global__ void k_cls(const unsigned short* __restrict__ h3, const unsigned short* __restrict__ wc1f,
                      const float* __restrict__ bc1, const float* __restrict__ Wc2,
                      const float* __restrict__ bc2, float* __restrict__ out, int N) {
    __shared__ unsigned short sA[64 * 136];
    __shared__ unsigned short sW[8192];   // 16 KB Wc1 frags
    int tid = threadIdx.x;
    int base = blockIdx.x * 64;
    const float4* wf4 = (const float4*)wc1f;
    float4* sW4 = (float4*)sW;
    #pragma unroll
    for (int i = 0; i < 4; ++i) sW4[tid + i * 256] = wf4[tid + i * 256];
    #pragma unroll
    for (int i = 0; i < 4; ++i) {
        int f = tid + i * 256;
        int row = f >> 4, c8 = f & 15;
        int n = base + row;
        uint4 v = (n < N) ? ((const uint4*)h3)[(size_t)n * 16 + c8]
                          : make_uint4(0u, 0u, 0u, 0u);
        *(uint4*)(&sA[row * 136 + c8 * 8]) = v;
    }
    __syncthreads();
    int wv = tid >> 6, lane = tid & 63;
    int q = lane >> 4, l15 = lane & 15;
    int rowbase = wv * 16;
    s8 af[4];
    #pragma unroll
    for (int kk = 0; kk < 4; ++kk)
        af[kk] = *(const s8*)(&sA[(rowbase + l15) * 136 + kk * 32 + q * 8]);
    float p[4][5];
    #pragma unroll
    for (int r = 0; r < 4; ++r)
        #pragma unroll
        for (int c = 0; c < 5; ++c) p[r][c] = 0.f;
    #pragma unroll
    for (int ct = 0; ct < 4; ++ct) {
        f4 acc = {0.f, 0.f, 0.f, 0.f};
        #pragma unroll
        for (int kk = 0; kk < 4; ++kk) {
            s8 bfr = *(const s8*)(&sW[((ct * 4 + kk) * 64 + lane) * 8]);
            acc = __builtin_amdgcn_mfma_f32_16x16x32_bf16(af[kk], bfr, acc, 0, 0, 0);
        }
        int col = ct * 16 + l15;
        float bcv = bc1[col];
        float w2v[5];
        #pragma unroll
        for (int c = 0; c < 5; ++c) w2v[c] = Wc2[col * 5 + c];
        #pragma unroll
        for (int r = 0; r < 4; ++r) {
            float t = fmaxf(acc[r] + bcv, 0.f);
            #pragma unroll
            for (int c = 0; c < 5; ++c) p[r][c] += t * w2v[c];
        }
    }
    #pragma unroll
    for (int m = 1; m < 16; m <<= 1) {
        #pragma unroll
        for (int r = 0; r < 4; ++r)
            #pragma unroll
            for (int c = 0; c < 5; ++c)
                p[r][c] += __shfl_xor(p[r][c], m, 64);
    }
    if (l15 == 0) {
        #pragma unroll
        for (int r = 0; r < 4; ++r) {
            int n = base + rowbase + q * 4 + r;
            if (n >= N) continue;
            float l[5], mx = -1e30f;
            #pragma unroll
            for (int c = 0; c < 5; ++c) { l[c] = p[r][c] + bc2[c]; mx = fmaxf(mx, l[c]); }
            float s = 0.f;
            #pragma unroll
            for (int c = 0; c < 5; ++c) s += __expf(l[c] - mx);
            float lse = mx + __logf(s);
            #pragma unroll
            for (int c = 0; c < 5; ++c) out[(size_t)n * 5 + c] = l[c] - lse;
        }
    }
}

extern "C" void kernel_launch(void* const* d_in, const int* in_sizes, int n_in,
                              void* d_out, int out_size, void* d_ws, size_t ws_size,
                              hipStream_t stream) {
    const float* x    = (const float*)d_in[0];
    const int*   ei   = (const int*)d_in[1];
    const float* attr = (const float*)d_in[2];
    const int*   mt   = (const int*)d_in[3];
    const int*   mg   = (const int*)d_in[4];
    const int*   mp   = (const int*)d_in[5];
    const float* Wf   = (const float*)d_in[24];
    const float* bf   = (const float*)d_in[25];
    const float* W2   = (const float*)d_in[26];
    const float* a2s  = (const float*)d_in[27];
    const float* a2d  = (const float*)d_in[28];
    const float* b2   = (const float*)d_in[29];
    const float* W3   = (const float*)d_in[30];
    const float* a3s  = (const float*)d_in[31];
    const float* a3d  = (const float*)d_in[32];
    const float* b3   = (const float*)d_in[33];
    const float* Wc1  = (const float*)d_in[34];
    const float* bc1  = (const float*)d_in[35];
    const float* Wc2  = (const float*)d_in[36];
    const float* bc2  = (const float*)d_in[37];

    int N = in_sizes[0];
    int E = in_sizes[1] / 2;

    char* w = (char*)d_ws;
    auto alloc = [&](size_t bytes) {
        char* p = w;
        w += (bytes + 255) & ~(size_t)255;
        return p;
    };
    int* off      = (int*)alloc((size_t)(N + 1) * 4);
    int* cursor   = (int*)alloc((size_t)N * 4);
    int* deg      = (int*)alloc((size_t)N * 4);
    int* partials = (int*)alloc(1024 * 4);
    int* csr_src  = (int*)alloc((size_t)E * 4);
    ConstBuf* cb  = (ConstBuf*)alloc(sizeof(ConstBuf));
    float* as_    = (float*)alloc((size_t)N * 4 * 4);
    float* ad_    = (float*)alloc((size_t)N * 4 * 4);
    unsigned short* xb = (unsigned short*)alloc((size_t)N * 256);  // h1/h2/h3 bf16
    float4* rec   = (float4*)alloc((size_t)E * 16);
    unsigned short* hxb = (unsigned short*)alloc((size_t)N * 256);
    unsigned short* wf2 = (unsigned short*)alloc(16384 * 2);
    unsigned short* wf3 = (unsigned short*)alloc(16384 * 2);
    unsigned short* wc1f = (unsigned short*)alloc(8192 * 2);

    PreArgs pa;
    for (int b = 0; b < 3; ++b) {
        pa.br[b].W   = (const float*)d_in[6 + b * 6 + 0];
        pa.br[b].as_ = (const float*)d_in[6 + b * 6 + 1];
        pa.br[b].ad_ = (const float*)d_in[6 + b * 6 + 2];
        pa.br[b].ae  = (const float*)d_in[6 + b * 6 + 3];
        pa.br[b].We  = (const float*)d_in[6 + b * 6 + 4];
        pa.br[b].b   = (const float*)d_in[6 + b * 6 + 5];
    }
    pa.Wf = Wf; pa.bf = bf; pa.cb = cb;

    int total = N + 1;
    int nScanBlocks = (total + SCAN_EPB - 1) / SCAN_EPB;

    hipLaunchKernelGGL(k_pre_all, dim3(4 + (N + 255) / 256), dim3(256), 0, stream,
                       pa, W2, wf2, W3, wf3, Wc1, wc1f, deg, N);
    int gE = (E + 255) / 256;
    hipLaunchKernelGGL(k_count, dim3(gE), dim3(256), 0, stream, ei, E, deg);
    hipLaunchKernelGGL(k_scan1, dim3(nScanBlocks), dim3(256), 0, stream, deg, off, partials, total);
    hipLaunchKernelGGL(k_scan3, dim3((total + 255) / 256), dim3(256), 0, stream,
                       off, partials, cursor, total);
    int chunk = (N + 7) / 8;
    hipLaunchKernelGGL(k_scatter, dim3(gE * 8), dim3(256), 0, stream,
                       ei, attr, mt, mg, mp, E, chunk, cursor, rec);
    hipLaunchKernelGGL(k_branch, dim3((N + 15) / 16), dim3(256), 0, stream,
                       x, off, rec, csr_src, cb, xb, N);
    // conv2
    hipLaunchKernelGGL(k_mm128b, dim3((N + 63) / 64), dim3(256), 0, stream,
                       xb, wf2, a2s, a2d, hxb, as_, ad_, N);
    hipLaunchKernelGGL(k_gatagg, dim3((N + 3) / 4), dim3(256), 0, stream,
                       hxb, as_, ad_, b2, off, csr_src, xb, N);
    // conv3
    hipLaunchKernelGGL(k_mm128b, dim3((N + 63) / 64), dim3(256), 0, stream,
                       xb, wf3, a3s, a3d, hxb, as_, ad_, N);
    hipLaunchKernelGGL(k_gatagg, dim3((N + 3) / 4), dim3(256), 0, stream,
                       hxb, as_, ad_, b3, off, csr_src, xb, N);
    // classifier (MFMA)
    hipLaunchKernelGGL(k_cls, dim3((N + 63) / 64), dim3(256), 0, stream,
                       xb, wc1f, bc1, Wc2, bc2, (float*)d_out, N);
}